// Round 1
// baseline (85673.224 us; speedup 1.0000x reference)
//
#include <hip/hip_runtime.h>
#include <hip/hip_cooperative_groups.h>

namespace cg = cooperative_groups;

typedef short short8 __attribute__((ext_vector_type(8)));
typedef float f32x4 __attribute__((ext_vector_type(4)));
typedef unsigned short u16x4 __attribute__((ext_vector_type(4)));

#define T_STEPS 2048
#define I_DIM   2048
#define H_DIM   4096
#define G_DIM   16384   // 4*H

__device__ __forceinline__ float bf2f(short s) {
    union { unsigned int u; float f; } v;
    v.u = ((unsigned int)(unsigned short)s) << 16;
    return v.f;
}
__device__ __forceinline__ unsigned short f2bf(float x) {
    union { float f; unsigned int u; } v; v.f = x;
    unsigned int u = v.u;
    return (unsigned short)((u + 0x7FFFu + ((u >> 16) & 1u)) >> 16);
}
__device__ __forceinline__ float sigmoidf_(float x) {
    return 1.0f / (1.0f + __expf(-x));
}

// ---------------- f32 -> bf16 conversion (for W_hh) ----------------
__global__ void convert_f32_bf16(const float* __restrict__ in,
                                 unsigned short* __restrict__ out, int n4) {
    int i = blockIdx.x * blockDim.x + threadIdx.x;
    int stride = gridDim.x * blockDim.x;
    for (; i < n4; i += stride) {
        f32x4 v = *(const f32x4*)(in + (size_t)i * 4);
        u16x4 o;
        o[0] = f2bf(v[0]); o[1] = f2bf(v[1]); o[2] = f2bf(v[2]); o[3] = f2bf(v[3]);
        *(u16x4*)(out + (size_t)i * 4) = o;
    }
}

__global__ void zero_f32(float* __restrict__ p, int n) {
    int i = blockIdx.x * blockDim.x + threadIdx.x;
    int stride = gridDim.x * blockDim.x;
    for (; i < n; i += stride) p[i] = 0.0f;
}

// ---------------- GEMM: G[t][r] = sum_k X[t][k]*W_ih[r][k] + bih[r]+bhh[r] ----------------
// A = X (f32, [M][K] row-major), B = W_ih (f32, [N][K] row-major, i.e. B^T GEMM)
// Converts f32->bf16 during LDS staging. 128x128 tile, BK=32, 4 waves (2x2 of 64x64).
__device__ __forceinline__ short8 cvt8(const float* __restrict__ p) {
    f32x4 a = *(const f32x4*)p;
    f32x4 b = *(const f32x4*)(p + 4);
    short8 r;
    r[0] = (short)f2bf(a[0]); r[1] = (short)f2bf(a[1]);
    r[2] = (short)f2bf(a[2]); r[3] = (short)f2bf(a[3]);
    r[4] = (short)f2bf(b[0]); r[5] = (short)f2bf(b[1]);
    r[6] = (short)f2bf(b[2]); r[7] = (short)f2bf(b[3]);
    return r;
}

__global__ __launch_bounds__(256) void gemm_bt(const float* __restrict__ A,
                                               const float* __restrict__ B,
                                               const float* __restrict__ bih,
                                               const float* __restrict__ bhh,
                                               float* __restrict__ C,
                                               int M, int N, int K) {
    __shared__ unsigned short As[128 * 32];
    __shared__ unsigned short Bs[128 * 32];
    const int bn = blockIdx.x, bm = blockIdx.y;
    const int tid = threadIdx.x;
    const int w = tid >> 6, l = tid & 63;
    const int wm = (w >> 1) * 64, wn = (w & 1) * 64;
    const int lr = l & 15, lk = (l >> 4) * 8;

    f32x4 acc[4][4];
#pragma unroll
    for (int mi = 0; mi < 4; mi++)
#pragma unroll
        for (int ni = 0; ni < 4; ni++) acc[mi][ni] = (f32x4)0.0f;

    const float* Ablk = A + (size_t)bm * 128 * K;
    const float* Bblk = B + (size_t)bn * 128 * K;

    for (int k0 = 0; k0 < K; k0 += 32) {
#pragma unroll
        for (int s = 0; s < 2; ++s) {
            int ch = tid + s * 256;
            int r = ch >> 2, kc = (ch & 3) * 8;
            ((short8*)As)[ch] = cvt8(Ablk + (size_t)r * K + k0 + kc);
            ((short8*)Bs)[ch] = cvt8(Bblk + (size_t)r * K + k0 + kc);
        }
        __syncthreads();
        short8 af[4], bfr[4];
#pragma unroll
        for (int mi = 0; mi < 4; mi++)
            af[mi] = *(const short8*)&As[(wm + mi * 16 + lr) * 32 + lk];
#pragma unroll
        for (int ni = 0; ni < 4; ni++)
            bfr[ni] = *(const short8*)&Bs[(wn + ni * 16 + lr) * 32 + lk];
#pragma unroll
        for (int mi = 0; mi < 4; mi++)
#pragma unroll
            for (int ni = 0; ni < 4; ni++)
                acc[mi][ni] = __builtin_amdgcn_mfma_f32_16x16x32_bf16(
                    af[mi], bfr[ni], acc[mi][ni], 0, 0, 0);
        __syncthreads();
    }

    const int cr = (l >> 4) * 4, cc = l & 15;
#pragma unroll
    for (int mi = 0; mi < 4; mi++) {
#pragma unroll
        for (int ni = 0; ni < 4; ni++) {
            int col = bn * 128 + wn + ni * 16 + cc;
            float bias = bih[col] + bhh[col];
#pragma unroll
            for (int r = 0; r < 4; r++) {
                int row = bm * 128 + wm + mi * 16 + cr + r;
                C[(size_t)row * N + col] = acc[mi][ni][r] + bias;
            }
        }
    }
}

// ---------------- Persistent recurrent kernel ----------------
// 256 WGs (1/CU) x 1024 threads (16 waves). WG b owns hidden units [16b, 16b+16).
// Per step: 64 complete W_hh-row dots (4 gates x 16 units), LSTM cell update on
// wave0 lanes 0..15 (c kept in LDS), h double-buffered in global, scalar readout
// partial via one atomicAdd per WG. One grid.sync per step.
__global__ __launch_bounds__(1024, 4) void lstm_seq(
        const unsigned short* __restrict__ Whh,   // bf16 [16384][4096]
        const float* __restrict__ G,              // [2048][16384]
        const float* __restrict__ Wlin,           // [4096]
        float* __restrict__ hbuf,                 // [2][4096]
        float* __restrict__ praw) {               // [2048]
    cg::grid_group grid = cg::this_grid();
    __shared__ float lds_g[64];
    __shared__ float c_lds[16];

    const int tid = threadIdx.x;
    const int base = blockIdx.x * 16;
    const int wave = tid >> 6, lane = tid & 63, li = lane & 15;
    const int rl = wave * 4 + (lane >> 4);     // 0..63: local row
    const int gate = rl >> 4, j = rl & 15;
    const int row = gate * H_DIM + base + j;   // global W_hh row
    const unsigned short* wrow = Whh + (size_t)row * H_DIM;

    if (tid < 16) c_lds[tid] = 0.0f;

    for (int t = 0; t < T_STEPS; t++) {
        const float* h = hbuf + (t & 1) * H_DIM;
        float* hn = hbuf + ((t + 1) & 1) * H_DIM;

        // prefetch this row's precomputed input-projection value (leaders only)
        float gval = (li == 0) ? G[(size_t)t * G_DIM + row] : 0.0f;

        float acc = 0.0f;
#pragma unroll 4
        for (int it = 0; it < 32; ++it) {
            int col = it * 128 + li * 8;
            short8 wv = *(const short8*)(wrow + col);
            f32x4 ha = *(const f32x4*)(h + col);
            f32x4 hb = *(const f32x4*)(h + col + 4);
            acc = fmaf(bf2f(wv[0]), ha[0], acc);
            acc = fmaf(bf2f(wv[1]), ha[1], acc);
            acc = fmaf(bf2f(wv[2]), ha[2], acc);
            acc = fmaf(bf2f(wv[3]), ha[3], acc);
            acc = fmaf(bf2f(wv[4]), hb[0], acc);
            acc = fmaf(bf2f(wv[5]), hb[1], acc);
            acc = fmaf(bf2f(wv[6]), hb[2], acc);
            acc = fmaf(bf2f(wv[7]), hb[3], acc);
        }
        // reduce over the 16 lanes of this row's lane-group
        acc += __shfl_xor(acc, 8, 16);
        acc += __shfl_xor(acc, 4, 16);
        acc += __shfl_xor(acc, 2, 16);
        acc += __shfl_xor(acc, 1, 16);
        if (li == 0) lds_g[rl] = acc + gval;
        __syncthreads();

        if (tid < 16) {
            float iv = sigmoidf_(lds_g[tid]);
            float fv = sigmoidf_(lds_g[16 + tid]);
            float gv = tanhf(lds_g[32 + tid]);
            float ov = sigmoidf_(lds_g[48 + tid]);
            float c = fv * c_lds[tid] + iv * gv;
            c_lds[tid] = c;
            float hv = ov * tanhf(c);
            hn[base + tid] = hv;
            float pp = hv * Wlin[base + tid];
            pp += __shfl_xor(pp, 8, 16);
            pp += __shfl_xor(pp, 4, 16);
            pp += __shfl_xor(pp, 2, 16);
            pp += __shfl_xor(pp, 1, 16);
            if (tid == 0) atomicAdd(praw + t, pp);
        }
        grid.sync();
    }
}

__global__ void finalize_out(const float* __restrict__ praw,
                             const float* __restrict__ blin,
                             float* __restrict__ out, int n) {
    int i = blockIdx.x * blockDim.x + threadIdx.x;
    if (i < n) out[i] = 1.0f / (1.0f + __expf(-(praw[i] + blin[0])));
}

// ---------------- launch ----------------
extern "C" void kernel_launch(void* const* d_in, const int* in_sizes, int n_in,
                              void* d_out, int out_size, void* d_ws, size_t ws_size,
                              hipStream_t stream) {
    const float* X    = (const float*)d_in[0];   // [2048][2048]
    const float* Wih  = (const float*)d_in[1];   // [16384][2048]
    const float* Whh  = (const float*)d_in[2];   // [16384][4096]
    const float* bih  = (const float*)d_in[3];   // [16384]
    const float* bhh  = (const float*)d_in[4];   // [16384]
    const float* Wlin = (const float*)d_in[5];   // [4096]
    const float* blin = (const float*)d_in[6];   // [1]
    float* out = (float*)d_out;                  // [2048]

    char* ws = (char*)d_ws;
    // layout (bytes):
    //   Whh16 : 0          .. 134217728   (16384*4096*2)
    //   G     : 134217728  .. 268435456   (2048*16384*4)
    //   hbuf  : 268435456  .. +32768      (2*4096*4)
    //   praw  : 268468224  .. +8192       (2048*4)
    unsigned short* Whh16 = (unsigned short*)(ws);
    float* G    = (float*)(ws + 134217728);
    float* hbuf = (float*)(ws + 268435456);
    float* praw = (float*)(ws + 268468224);

    convert_f32_bf16<<<dim3(2048), dim3(256), 0, stream>>>(Whh, Whh16,
                                                           (16384 * 4096) / 4);
    zero_f32<<<dim3(16), dim3(256), 0, stream>>>(hbuf, 8192 + 2048);
    gemm_bt<<<dim3(128, 16), dim3(256), 0, stream>>>(X, Wih, bih, bhh, G,
                                                     2048, 16384, 2048);

    void* args[] = { (void*)&Whh16, (void*)&G, (void*)&Wlin,
                     (void*)&hbuf, (void*)&praw };
    hipLaunchCooperativeKernel((void*)lstm_seq, dim3(256), dim3(1024),
                               args, 0, stream);

    finalize_out<<<dim3(8), dim3(256), 0, stream>>>(praw, blin, out, 2048);
}

// Round 2
// 62205.194 us; speedup vs baseline: 1.3773x; 1.3773x over previous
//
#include <hip/hip_runtime.h>
#include <hip/hip_cooperative_groups.h>

namespace cg = cooperative_groups;

typedef short  short8 __attribute__((ext_vector_type(8)));
typedef float  f32x4  __attribute__((ext_vector_type(4)));
typedef _Float16 half8_t __attribute__((ext_vector_type(8)));
typedef _Float16 half2_t __attribute__((ext_vector_type(2)));

#define T_STEPS 2048
#define I_DIM   2048
#define H_DIM   4096
#define G_DIM   16384   // 4*H

__device__ __forceinline__ unsigned short f2bf(float x) {
    union { float f; unsigned int u; } v; v.f = x;
    unsigned int u = v.u;
    return (unsigned short)((u + 0x7FFFu + ((u >> 16) & 1u)) >> 16);
}
__device__ __forceinline__ float sigmoidf_(float x) {
    return 1.0f / (1.0f + __expf(-x));
}

__device__ __forceinline__ float dot2f(half2_t a, half2_t b, float acc) {
#if __has_builtin(__builtin_amdgcn_fdot2)
    return __builtin_amdgcn_fdot2(a, b, acc, false);
#else
    return fmaf((float)a[0], (float)b[0], fmaf((float)a[1], (float)b[1], acc));
#endif
}
__device__ __forceinline__ float dot8f(half8_t a, half8_t b, float acc) {
    acc = dot2f(__builtin_shufflevector(a, a, 0, 1), __builtin_shufflevector(b, b, 0, 1), acc);
    acc = dot2f(__builtin_shufflevector(a, a, 2, 3), __builtin_shufflevector(b, b, 2, 3), acc);
    acc = dot2f(__builtin_shufflevector(a, a, 4, 5), __builtin_shufflevector(b, b, 4, 5), acc);
    acc = dot2f(__builtin_shufflevector(a, a, 6, 7), __builtin_shufflevector(b, b, 6, 7), acc);
    return acc;
}

// ---------------- f32 -> f16 conversion (for W_hh) ----------------
__global__ void convert_f32_f16(const float* __restrict__ in,
                                _Float16* __restrict__ out, int n8) {
    int i = blockIdx.x * blockDim.x + threadIdx.x;
    int stride = gridDim.x * blockDim.x;
    for (; i < n8; i += stride) {
        f32x4 a = *(const f32x4*)(in + (size_t)i * 8);
        f32x4 b = *(const f32x4*)(in + (size_t)i * 8 + 4);
        half8_t o;
        o[0] = (_Float16)a[0]; o[1] = (_Float16)a[1];
        o[2] = (_Float16)a[2]; o[3] = (_Float16)a[3];
        o[4] = (_Float16)b[0]; o[5] = (_Float16)b[1];
        o[6] = (_Float16)b[2]; o[7] = (_Float16)b[3];
        *(half8_t*)(out + (size_t)i * 8) = o;
    }
}

__global__ void zero_f32(float* __restrict__ p, int n) {
    int i = blockIdx.x * blockDim.x + threadIdx.x;
    int stride = gridDim.x * blockDim.x;
    for (; i < n; i += stride) p[i] = 0.0f;
}

// ---------------- GEMM: G[t][r] = sum_k X[t][k]*W_ih[r][k] + bih[r]+bhh[r] ----------------
__device__ __forceinline__ short8 cvt8(const float* __restrict__ p) {
    f32x4 a = *(const f32x4*)p;
    f32x4 b = *(const f32x4*)(p + 4);
    short8 r;
    r[0] = (short)f2bf(a[0]); r[1] = (short)f2bf(a[1]);
    r[2] = (short)f2bf(a[2]); r[3] = (short)f2bf(a[3]);
    r[4] = (short)f2bf(b[0]); r[5] = (short)f2bf(b[1]);
    r[6] = (short)f2bf(b[2]); r[7] = (short)f2bf(b[3]);
    return r;
}

__global__ __launch_bounds__(256) void gemm_bt(const float* __restrict__ A,
                                               const float* __restrict__ B,
                                               const float* __restrict__ bih,
                                               const float* __restrict__ bhh,
                                               _Float16* __restrict__ C,
                                               int M, int N, int K) {
    __shared__ unsigned short As[128 * 32];
    __shared__ unsigned short Bs[128 * 32];
    const int bn = blockIdx.x, bm = blockIdx.y;
    const int tid = threadIdx.x;
    const int w = tid >> 6, l = tid & 63;
    const int wm = (w >> 1) * 64, wn = (w & 1) * 64;
    const int lr = l & 15, lk = (l >> 4) * 8;

    f32x4 acc[4][4];
#pragma unroll
    for (int mi = 0; mi < 4; mi++)
#pragma unroll
        for (int ni = 0; ni < 4; ni++) acc[mi][ni] = (f32x4)0.0f;

    const float* Ablk = A + (size_t)bm * 128 * K;
    const float* Bblk = B + (size_t)bn * 128 * K;

    for (int k0 = 0; k0 < K; k0 += 32) {
#pragma unroll
        for (int s = 0; s < 2; ++s) {
            int ch = tid + s * 256;
            int r = ch >> 2, kc = (ch & 3) * 8;
            ((short8*)As)[ch] = cvt8(Ablk + (size_t)r * K + k0 + kc);
            ((short8*)Bs)[ch] = cvt8(Bblk + (size_t)r * K + k0 + kc);
        }
        __syncthreads();
        short8 af[4], bfr[4];
#pragma unroll
        for (int mi = 0; mi < 4; mi++)
            af[mi] = *(const short8*)&As[(wm + mi * 16 + lr) * 32 + lk];
#pragma unroll
        for (int ni = 0; ni < 4; ni++)
            bfr[ni] = *(const short8*)&Bs[(wn + ni * 16 + lr) * 32 + lk];
#pragma unroll
        for (int mi = 0; mi < 4; mi++)
#pragma unroll
            for (int ni = 0; ni < 4; ni++)
                acc[mi][ni] = __builtin_amdgcn_mfma_f32_16x16x32_bf16(
                    af[mi], bfr[ni], acc[mi][ni], 0, 0, 0);
        __syncthreads();
    }

    const int cr = (l >> 4) * 4, cc = l & 15;
#pragma unroll
    for (int mi = 0; mi < 4; mi++) {
#pragma unroll
        for (int ni = 0; ni < 4; ni++) {
            int col = bn * 128 + wn + ni * 16 + cc;
            float bias = bih[col] + bhh[col];
#pragma unroll
            for (int r = 0; r < 4; r++) {
                int row = bm * 128 + wm + mi * 16 + cr + r;
                C[(size_t)row * N + col] = (_Float16)(acc[mi][ni][r] + bias);
            }
        }
    }
}

// ---------------- Persistent recurrent kernel (weights on-chip) ----------------
// 256 WGs x 512 threads (2 waves/SIMD). WG b owns 64 W_hh rows: {g*4096+16b+u}.
// Per thread: 8 rows x 64 cols; cols chunked 8x: chunk c -> cols c*512 + l*8 .. +8.
// Chunks 0..5 live in 192 VGPRs (half8 wr[8][6]); chunks 6..7 in LDS (128 KiB).
// h: f16, double-buffered in global (8 KB), staged to LDS each step.
// Row reduce: LDS transpose part[64][65] (+1 pad, conflict-free both sides).
__global__ __launch_bounds__(512, 2) void lstm_seq(
        const _Float16* __restrict__ W,      // f16 [16384][4096]
        const _Float16* __restrict__ G,      // f16 [2048][16384]
        const float* __restrict__ Wlin,      // [4096]
        _Float16* __restrict__ hbuf,         // f16 [2][4096]
        float* __restrict__ praw_part) {     // [256][2048]
    cg::grid_group grid = cg::this_grid();
    extern __shared__ char smem[];
    _Float16* wl  = (_Float16*)smem;                  // [128][512] = 128 KiB
    _Float16* hl  = (_Float16*)(smem + 131072);       // [4096]     = 8 KiB
    float*    part = (float*)(smem + 131072 + 8192);  // [64][65]   = 16.25 KiB

    const int tid = threadIdx.x;
    const int w = tid >> 6, l = tid & 63;
    const int base = blockIdx.x * 16;

    // ---- one-time: load persistent weights ----
    half8_t wr[8][6];
#pragma unroll
    for (int rr = 0; rr < 8; ++rr) {
        const int rl = w * 8 + rr;
        const size_t grow = (size_t)((rl >> 4) * H_DIM + base + (rl & 15));
        const _Float16* wp = W + grow * H_DIM + l * 8;
#pragma unroll
        for (int c = 0; c < 6; ++c)
            wr[rr][c] = *(const half8_t*)(wp + c * 512);
    }
    for (int i = tid; i < 8192; i += 512) {   // 128 KiB staged: rl*2+c2 rows of 512
        int col8 = i & 63;
        int cr   = i >> 6;                    // rl*2 + c2
        int rl = cr >> 1, c2 = cr & 1;
        size_t grow = (size_t)((rl >> 4) * H_DIM + base + (rl & 15));
        *(half8_t*)(wl + cr * 512 + col8 * 8) =
            *(const half8_t*)(W + grow * H_DIM + (6 + c2) * 512 + col8 * 8);
    }

    float creg = 0.0f;

#pragma unroll 1
    for (int t = 0; t < T_STEPS; ++t) {
        const _Float16* hprev = hbuf + (t & 1) * H_DIM;
        // stage h into LDS (512 x 16B)
        *(half8_t*)(hl + tid * 8) = *(const half8_t*)(hprev + tid * 8);
        __syncthreads();

        float acc[8];
#pragma unroll
        for (int rr = 0; rr < 8; ++rr) acc[rr] = 0.0f;

#pragma unroll
        for (int c = 0; c < 6; ++c) {
            half8_t hv = *(const half8_t*)(hl + c * 512 + l * 8);
#pragma unroll
            for (int rr = 0; rr < 8; ++rr)
                acc[rr] = dot8f(wr[rr][c], hv, acc[rr]);
        }
#pragma unroll
        for (int c2 = 0; c2 < 2; ++c2) {
            half8_t hv = *(const half8_t*)(hl + (6 + c2) * 512 + l * 8);
#pragma unroll
            for (int rr = 0; rr < 8; ++rr) {
                half8_t wv = *(const half8_t*)(wl + ((w * 8 + rr) * 2 + c2) * 512 + l * 8);
                acc[rr] = dot8f(wv, hv, acc[rr]);
            }
        }
#pragma unroll
        for (int rr = 0; rr < 8; ++rr)
            part[(w * 8 + rr) * 65 + l] = acc[rr];
        __syncthreads();

        if (tid < 64) {
            const float* pr = part + tid * 65;
            float s0 = 0.f, s1 = 0.f, s2 = 0.f, s3 = 0.f;
#pragma unroll
            for (int j = 0; j < 16; ++j) {
                s0 += pr[4 * j + 0]; s1 += pr[4 * j + 1];
                s2 += pr[4 * j + 2]; s3 += pr[4 * j + 3];
            }
            const int grow = (tid >> 4) * H_DIM + base + (tid & 15);
            float s = (s0 + s1) + (s2 + s3) + (float)G[(size_t)t * G_DIM + grow];
            float fv = __shfl(s, (tid & 15) + 16);
            float gv = __shfl(s, (tid & 15) + 32);
            float ov = __shfl(s, (tid & 15) + 48);
            if (tid < 16) {
                float c = sigmoidf_(fv) * creg + sigmoidf_(s) * tanhf(gv);
                creg = c;
                float hv = sigmoidf_(ov) * tanhf(c);
                hbuf[((t + 1) & 1) * H_DIM + base + tid] = (_Float16)hv;
                float pp = hv * Wlin[base + tid];
                pp += __shfl_xor(pp, 8, 16);
                pp += __shfl_xor(pp, 4, 16);
                pp += __shfl_xor(pp, 2, 16);
                pp += __shfl_xor(pp, 1, 16);
                if (tid == 0) praw_part[(size_t)blockIdx.x * T_STEPS + t] = pp;
            }
        }
        grid.sync();
    }
}

__global__ void finalize_out(const float* __restrict__ praw_part,
                             const float* __restrict__ blin,
                             float* __restrict__ out, int n) {
    int i = blockIdx.x * blockDim.x + threadIdx.x;
    if (i < n) {
        float s = blin[0];
        for (int wg = 0; wg < 256; ++wg)
            s += praw_part[(size_t)wg * T_STEPS + i];
        out[i] = 1.0f / (1.0f + __expf(-s));
    }
}

// ---------------- launch ----------------
extern "C" void kernel_launch(void* const* d_in, const int* in_sizes, int n_in,
                              void* d_out, int out_size, void* d_ws, size_t ws_size,
                              hipStream_t stream) {
    const float* X    = (const float*)d_in[0];   // [2048][2048]
    const float* Wih  = (const float*)d_in[1];   // [16384][2048]
    const float* Whh  = (const float*)d_in[2];   // [16384][4096]
    const float* bih  = (const float*)d_in[3];   // [16384]
    const float* bhh  = (const float*)d_in[4];   // [16384]
    const float* Wlin = (const float*)d_in[5];   // [4096]
    const float* blin = (const float*)d_in[6];   // [1]
    float* out = (float*)d_out;                  // [2048]

    char* ws = (char*)d_ws;
    // layout (bytes):
    //   Whh16 (f16): 0          .. 134217728   (16384*4096*2)
    //   G     (f16): 134217728  .. 201326592   (2048*16384*2)
    //   hbuf  (f16): 201326592  .. +16384      (2*4096*2)
    //   praw_part  : 201342976  .. +2097152    (256*2048*4)
    _Float16* Whh16 = (_Float16*)(ws);
    _Float16* G     = (_Float16*)(ws + 134217728);
    _Float16* hbuf  = (_Float16*)(ws + 201326592);
    float* praw_part = (float*)(ws + 201342976);

    convert_f32_f16<<<dim3(2048), dim3(256), 0, stream>>>(Whh, Whh16,
                                                          (16384 * 4096) / 8);
    zero_f32<<<dim3(16), dim3(256), 0, stream>>>((float*)hbuf, 4096);
    gemm_bt<<<dim3(128, 16), dim3(256), 0, stream>>>(X, Wih, bih, bhh, G,
                                                     2048, 16384, 2048);

    static int attr_set = 0;
    (void)attr_set;
    hipFuncSetAttribute((const void*)lstm_seq,
                        hipFuncAttributeMaxDynamicSharedMemorySize, 160 * 1024);

    void* args[] = { (void*)&Whh16, (void*)&G, (void*)&Wlin,
                     (void*)&hbuf, (void*)&praw_part };
    hipLaunchCooperativeKernel((void*)lstm_seq, dim3(256), dim3(512),
                               args, 155904, stream);

    finalize_out<<<dim3(8), dim3(256), 0, stream>>>(praw_part, blin, out, 2048);
}

// Round 3
// 60078.705 us; speedup vs baseline: 1.4260x; 1.0354x over previous
//
#include <hip/hip_runtime.h>
#include <hip/hip_cooperative_groups.h>

namespace cg = cooperative_groups;

typedef short  short8 __attribute__((ext_vector_type(8)));
typedef float  f32x4  __attribute__((ext_vector_type(4)));
typedef _Float16 half8_t __attribute__((ext_vector_type(8)));
typedef _Float16 half2_t __attribute__((ext_vector_type(2)));

#define T_STEPS 2048
#define I_DIM   2048
#define H_DIM   4096
#define G_DIM   16384   // 4*H

__device__ __forceinline__ unsigned short f2bf(float x) {
    union { float f; unsigned int u; } v; v.f = x;
    unsigned int u = v.u;
    return (unsigned short)((u + 0x7FFFu + ((u >> 16) & 1u)) >> 16);
}
__device__ __forceinline__ float sigmoidf_(float x) {
    return 1.0f / (1.0f + __expf(-x));
}

__device__ __forceinline__ float dot2f(half2_t a, half2_t b, float acc) {
#if __has_builtin(__builtin_amdgcn_fdot2)
    return __builtin_amdgcn_fdot2(a, b, acc, false);
#else
    return fmaf((float)a[0], (float)b[0], fmaf((float)a[1], (float)b[1], acc));
#endif
}
__device__ __forceinline__ float dot8f(half8_t a, half8_t b, float acc) {
    acc = dot2f(__builtin_shufflevector(a, a, 0, 1), __builtin_shufflevector(b, b, 0, 1), acc);
    acc = dot2f(__builtin_shufflevector(a, a, 2, 3), __builtin_shufflevector(b, b, 2, 3), acc);
    acc = dot2f(__builtin_shufflevector(a, a, 4, 5), __builtin_shufflevector(b, b, 4, 5), acc);
    acc = dot2f(__builtin_shufflevector(a, a, 6, 7), __builtin_shufflevector(b, b, 6, 7), acc);
    return acc;
}

// ---------------- f32 -> f16 conversion (for W_hh) ----------------
__global__ void convert_f32_f16(const float* __restrict__ in,
                                _Float16* __restrict__ out, int n8) {
    int i = blockIdx.x * blockDim.x + threadIdx.x;
    int stride = gridDim.x * blockDim.x;
    for (; i < n8; i += stride) {
        f32x4 a = *(const f32x4*)(in + (size_t)i * 8);
        f32x4 b = *(const f32x4*)(in + (size_t)i * 8 + 4);
        half8_t o;
        o[0] = (_Float16)a[0]; o[1] = (_Float16)a[1];
        o[2] = (_Float16)a[2]; o[3] = (_Float16)a[3];
        o[4] = (_Float16)b[0]; o[5] = (_Float16)b[1];
        o[6] = (_Float16)b[2]; o[7] = (_Float16)b[3];
        *(half8_t*)(out + (size_t)i * 8) = o;
    }
}

__global__ void zero_f32(float* __restrict__ p, int n) {
    int i = blockIdx.x * blockDim.x + threadIdx.x;
    int stride = gridDim.x * blockDim.x;
    for (; i < n; i += stride) p[i] = 0.0f;
}

// ---------------- GEMM: G[t][r] = sum_k X[t][k]*W_ih[r][k] + bih[r]+bhh[r] ----------------
__device__ __forceinline__ short8 cvt8(const float* __restrict__ p) {
    f32x4 a = *(const f32x4*)p;
    f32x4 b = *(const f32x4*)(p + 4);
    short8 r;
    r[0] = (short)f2bf(a[0]); r[1] = (short)f2bf(a[1]);
    r[2] = (short)f2bf(a[2]); r[3] = (short)f2bf(a[3]);
    r[4] = (short)f2bf(b[0]); r[5] = (short)f2bf(b[1]);
    r[6] = (short)f2bf(b[2]); r[7] = (short)f2bf(b[3]);
    return r;
}

__global__ __launch_bounds__(256) void gemm_bt(const float* __restrict__ A,
                                               const float* __restrict__ B,
                                               const float* __restrict__ bih,
                                               const float* __restrict__ bhh,
                                               _Float16* __restrict__ C,
                                               int M, int N, int K) {
    __shared__ unsigned short As[128 * 32];
    __shared__ unsigned short Bs[128 * 32];
    const int bn = blockIdx.x, bm = blockIdx.y;
    const int tid = threadIdx.x;
    const int w = tid >> 6, l = tid & 63;
    const int wm = (w >> 1) * 64, wn = (w & 1) * 64;
    const int lr = l & 15, lk = (l >> 4) * 8;

    f32x4 acc[4][4];
#pragma unroll
    for (int mi = 0; mi < 4; mi++)
#pragma unroll
        for (int ni = 0; ni < 4; ni++) acc[mi][ni] = (f32x4)0.0f;

    const float* Ablk = A + (size_t)bm * 128 * K;
    const float* Bblk = B + (size_t)bn * 128 * K;

    for (int k0 = 0; k0 < K; k0 += 32) {
#pragma unroll
        for (int s = 0; s < 2; ++s) {
            int ch = tid + s * 256;
            int r = ch >> 2, kc = (ch & 3) * 8;
            ((short8*)As)[ch] = cvt8(Ablk + (size_t)r * K + k0 + kc);
            ((short8*)Bs)[ch] = cvt8(Bblk + (size_t)r * K + k0 + kc);
        }
        __syncthreads();
        short8 af[4], bfr[4];
#pragma unroll
        for (int mi = 0; mi < 4; mi++)
            af[mi] = *(const short8*)&As[(wm + mi * 16 + lr) * 32 + lk];
#pragma unroll
        for (int ni = 0; ni < 4; ni++)
            bfr[ni] = *(const short8*)&Bs[(wn + ni * 16 + lr) * 32 + lk];
#pragma unroll
        for (int mi = 0; mi < 4; mi++)
#pragma unroll
            for (int ni = 0; ni < 4; ni++)
                acc[mi][ni] = __builtin_amdgcn_mfma_f32_16x16x32_bf16(
                    af[mi], bfr[ni], acc[mi][ni], 0, 0, 0);
        __syncthreads();
    }

    const int cr = (l >> 4) * 4, cc = l & 15;
#pragma unroll
    for (int mi = 0; mi < 4; mi++) {
#pragma unroll
        for (int ni = 0; ni < 4; ni++) {
            int col = bn * 128 + wn + ni * 16 + cc;
            float bias = bih[col] + bhh[col];
#pragma unroll
            for (int r = 0; r < 4; r++) {
                int row = bm * 128 + wm + mi * 16 + cr + r;
                C[(size_t)row * N + col] = (_Float16)(acc[mi][ni][r] + bias);
            }
        }
    }
}

// ---------------- Persistent recurrent kernel (weights pinned on-chip) ----------------
// 256 WGs x 512 threads (2 waves/SIMD). WG b owns 64 W_hh rows: {g*4096+16b+u}.
// Per thread: 8 rows x 64 cols; cols chunked 8x: chunk c -> cols c*512 + l*8 .. +8.
// Chunks 0..5 PINNED in 192 VGPRs (asm keep-alive defeats rematerialization —
// round-2's VGPR_Count=120 proved the compiler was re-loading 96 MB/step from L3).
// Chunks 6..7 in LDS (128 KiB). h: f16 double-buffered in global, staged to LDS.
__global__ __launch_bounds__(512, 2) void lstm_seq(
        const _Float16* __restrict__ W,      // f16 [16384][4096]
        const _Float16* __restrict__ G,      // f16 [2048][16384]
        const float* __restrict__ Wlin,      // [4096]
        _Float16* __restrict__ hbuf,         // f16 [2][4096]
        float* __restrict__ praw_part) {     // [256][2048]
    cg::grid_group grid = cg::this_grid();
    extern __shared__ char smem[];
    _Float16* wl  = (_Float16*)smem;                  // [128][512] = 128 KiB
    _Float16* hl  = (_Float16*)(smem + 131072);       // [4096]     = 8 KiB
    float*    part = (float*)(smem + 131072 + 8192);  // [64][65]   = 16.25 KiB

    const int tid = threadIdx.x;
    const int w = tid >> 6, l = tid & 63;
    const int base = blockIdx.x * 16;

    // ---- one-time: load persistent weights ----
    half8_t wr[8][6];
#pragma unroll
    for (int rr = 0; rr < 8; ++rr) {
        const int rl = w * 8 + rr;
        const size_t grow = (size_t)((rl >> 4) * H_DIM + base + (rl & 15));
        const _Float16* wp = W + grow * H_DIM + l * 8;
#pragma unroll
        for (int c = 0; c < 6; ++c)
            wr[rr][c] = *(const half8_t*)(wp + c * 512);
    }
    for (int i = tid; i < 8192; i += 512) {   // LDS part: chunks 6,7
        int col8 = i & 63;
        int cr   = i >> 6;                    // rl*2 + c2
        int rl = cr >> 1, c2 = cr & 1;
        size_t grow = (size_t)((rl >> 4) * H_DIM + base + (rl & 15));
        *(half8_t*)(wl + cr * 512 + col8 * 8) =
            *(const half8_t*)(W + grow * H_DIM + (6 + c2) * 512 + col8 * 8);
    }

    // ---- PIN the register weights: opaque asm keep-alive ----
#pragma unroll
    for (int rr = 0; rr < 8; ++rr)
#pragma unroll
        for (int c = 0; c < 6; ++c) {
            f32x4 t = __builtin_bit_cast(f32x4, wr[rr][c]);
            asm volatile("" : "+v"(t));
            wr[rr][c] = __builtin_bit_cast(half8_t, t);
        }

    // loop-invariant hoists
    const float wlin = (tid < 16) ? Wlin[base + tid] : 0.0f;
    const int grow_g = (tid >> 4) * H_DIM + base + (tid & 15);  // valid for tid<64
    const _Float16* wlbase = wl + (w * 16) * 512 + l * 8;
    const _Float16* hlbase = hl + l * 8;

    float creg = 0.0f;

#pragma unroll 1
    for (int t = 0; t < T_STEPS; ++t) {
        // prefetch this step's input-projection values early (wave 0 only)
        float gval = 0.0f;
        if (tid < 64) gval = (float)G[(size_t)t * G_DIM + grow_g];

        const _Float16* hprev = hbuf + (t & 1) * H_DIM;
        *(half8_t*)(hl + tid * 8) = *(const half8_t*)(hprev + tid * 8);
        __syncthreads();

        float acc[8];
#pragma unroll
        for (int rr = 0; rr < 8; ++rr) acc[rr] = 0.0f;

#pragma unroll
        for (int c = 0; c < 6; ++c) {
            half8_t hv = *(const half8_t*)(hlbase + c * 512);
#pragma unroll
            for (int rr = 0; rr < 8; ++rr)
                acc[rr] = dot8f(wr[rr][c], hv, acc[rr]);
        }
#pragma unroll
        for (int c2 = 0; c2 < 2; ++c2) {
            half8_t hv = *(const half8_t*)(hlbase + (6 + c2) * 512);
#pragma unroll
            for (int rr = 0; rr < 8; ++rr) {
                half8_t wv = *(const half8_t*)(wlbase + (rr * 2 + c2) * 512);
                acc[rr] = dot8f(wv, hv, acc[rr]);
            }
        }
#pragma unroll
        for (int rr = 0; rr < 8; ++rr)
            part[(w * 8 + rr) * 65 + l] = acc[rr];
        __syncthreads();

        if (tid < 64) {
            const float* pr = part + tid * 65;
            float s0 = 0.f, s1 = 0.f, s2 = 0.f, s3 = 0.f;
#pragma unroll
            for (int j = 0; j < 16; ++j) {
                s0 += pr[4 * j + 0]; s1 += pr[4 * j + 1];
                s2 += pr[4 * j + 2]; s3 += pr[4 * j + 3];
            }
            float s = (s0 + s1) + (s2 + s3) + gval;
            float fv = __shfl(s, (tid & 15) + 16);
            float gv = __shfl(s, (tid & 15) + 32);
            float ov = __shfl(s, (tid & 15) + 48);
            if (tid < 16) {
                float c = sigmoidf_(fv) * creg + sigmoidf_(s) * tanhf(gv);
                creg = c;
                float hv = sigmoidf_(ov) * tanhf(c);
                hbuf[((t + 1) & 1) * H_DIM + base + tid] = (_Float16)hv;
                float pp = hv * wlin;
                pp += __shfl_xor(pp, 8, 16);
                pp += __shfl_xor(pp, 4, 16);
                pp += __shfl_xor(pp, 2, 16);
                pp += __shfl_xor(pp, 1, 16);
                if (tid == 0) praw_part[(size_t)blockIdx.x * T_STEPS + t] = pp;
            }
        }
        grid.sync();
    }
}

__global__ void finalize_out(const float* __restrict__ praw_part,
                             const float* __restrict__ blin,
                             float* __restrict__ out, int n) {
    int i = blockIdx.x * blockDim.x + threadIdx.x;
    if (i < n) {
        float s = blin[0];
        for (int wg = 0; wg < 256; ++wg)
            s += praw_part[(size_t)wg * T_STEPS + i];
        out[i] = 1.0f / (1.0f + __expf(-s));
    }
}

// ---------------- launch ----------------
extern "C" void kernel_launch(void* const* d_in, const int* in_sizes, int n_in,
                              void* d_out, int out_size, void* d_ws, size_t ws_size,
                              hipStream_t stream) {
    const float* X    = (const float*)d_in[0];   // [2048][2048]
    const float* Wih  = (const float*)d_in[1];   // [16384][2048]
    const float* Whh  = (const float*)d_in[2];   // [16384][4096]
    const float* bih  = (const float*)d_in[3];   // [16384]
    const float* bhh  = (const float*)d_in[4];   // [16384]
    const float* Wlin = (const float*)d_in[5];   // [4096]
    const float* blin = (const float*)d_in[6];   // [1]
    float* out = (float*)d_out;                  // [2048]

    char* ws = (char*)d_ws;
    _Float16* Whh16 = (_Float16*)(ws);
    _Float16* G     = (_Float16*)(ws + 134217728);
    _Float16* hbuf  = (_Float16*)(ws + 201326592);
    float* praw_part = (float*)(ws + 201342976);

    convert_f32_f16<<<dim3(2048), dim3(256), 0, stream>>>(Whh, Whh16,
                                                          (16384 * 4096) / 8);
    zero_f32<<<dim3(16), dim3(256), 0, stream>>>((float*)hbuf, 4096);
    gemm_bt<<<dim3(128, 16), dim3(256), 0, stream>>>(X, Wih, bih, bhh, G,
                                                     2048, 16384, 2048);

    hipFuncSetAttribute((const void*)lstm_seq,
                        hipFuncAttributeMaxDynamicSharedMemorySize, 160 * 1024);

    void* args[] = { (void*)&Whh16, (void*)&G, (void*)&Wlin,
                     (void*)&hbuf, (void*)&praw_part };
    hipLaunchCooperativeKernel((void*)lstm_seq, dim3(256), dim3(512),
                               args, 155904, stream);

    finalize_out<<<dim3(8), dim3(256), 0, stream>>>(praw_part, blin, out, 2048);
}

// Round 4
// 17744.867 us; speedup vs baseline: 4.8281x; 3.3857x over previous
//
#include <hip/hip_runtime.h>

typedef short  short8 __attribute__((ext_vector_type(8)));
typedef float  f32x4  __attribute__((ext_vector_type(4)));
typedef _Float16 half8_t __attribute__((ext_vector_type(8)));
typedef _Float16 half2_t __attribute__((ext_vector_type(2)));

#define T_STEPS 2048
#define I_DIM   2048
#define H_DIM   4096
#define G_DIM   16384   // 4*H

__device__ __forceinline__ unsigned short f2bf(float x) {
    union { float f; unsigned int u; } v; v.f = x;
    unsigned int u = v.u;
    return (unsigned short)((u + 0x7FFFu + ((u >> 16) & 1u)) >> 16);
}
__device__ __forceinline__ float sigmoidf_(float x) {
    return 1.0f / (1.0f + __expf(-x));
}

__device__ __forceinline__ float dot2f(half2_t a, half2_t b, float acc) {
#if __has_builtin(__builtin_amdgcn_fdot2)
    return __builtin_amdgcn_fdot2(a, b, acc, false);
#else
    return fmaf((float)a[0], (float)b[0], fmaf((float)a[1], (float)b[1], acc));
#endif
}
__device__ __forceinline__ float dot8f(half8_t a, half8_t b, float acc) {
    acc = dot2f(__builtin_shufflevector(a, a, 0, 1), __builtin_shufflevector(b, b, 0, 1), acc);
    acc = dot2f(__builtin_shufflevector(a, a, 2, 3), __builtin_shufflevector(b, b, 2, 3), acc);
    acc = dot2f(__builtin_shufflevector(a, a, 4, 5), __builtin_shufflevector(b, b, 4, 5), acc);
    acc = dot2f(__builtin_shufflevector(a, a, 6, 7), __builtin_shufflevector(b, b, 6, 7), acc);
    return acc;
}

// ---------------- f32 -> f16 conversion (for W_hh) ----------------
__global__ void convert_f32_f16(const float* __restrict__ in,
                                _Float16* __restrict__ out, int n8) {
    int i = blockIdx.x * blockDim.x + threadIdx.x;
    int stride = gridDim.x * blockDim.x;
    for (; i < n8; i += stride) {
        f32x4 a = *(const f32x4*)(in + (size_t)i * 8);
        f32x4 b = *(const f32x4*)(in + (size_t)i * 8 + 4);
        half8_t o;
        o[0] = (_Float16)a[0]; o[1] = (_Float16)a[1];
        o[2] = (_Float16)a[2]; o[3] = (_Float16)a[3];
        o[4] = (_Float16)b[0]; o[5] = (_Float16)b[1];
        o[6] = (_Float16)b[2]; o[7] = (_Float16)b[3];
        *(half8_t*)(out + (size_t)i * 8) = o;
    }
}

__global__ void zero_f32(float* __restrict__ p, int n) {
    int i = blockIdx.x * blockDim.x + threadIdx.x;
    int stride = gridDim.x * blockDim.x;
    for (; i < n; i += stride) p[i] = 0.0f;
}

// ---------------- GEMM: G[t][r] = sum_k X[t][k]*W_ih[r][k] + bih[r]+bhh[r] ----------------
__device__ __forceinline__ short8 cvt8(const float* __restrict__ p) {
    f32x4 a = *(const f32x4*)p;
    f32x4 b = *(const f32x4*)(p + 4);
    short8 r;
    r[0] = (short)f2bf(a[0]); r[1] = (short)f2bf(a[1]);
    r[2] = (short)f2bf(a[2]); r[3] = (short)f2bf(a[3]);
    r[4] = (short)f2bf(b[0]); r[5] = (short)f2bf(b[1]);
    r[6] = (short)f2bf(b[2]); r[7] = (short)f2bf(b[3]);
    return r;
}

__global__ __launch_bounds__(256) void gemm_bt(const float* __restrict__ A,
                                               const float* __restrict__ B,
                                               const float* __restrict__ bih,
                                               const float* __restrict__ bhh,
                                               _Float16* __restrict__ C,
                                               int M, int N, int K) {
    __shared__ unsigned short As[128 * 32];
    __shared__ unsigned short Bs[128 * 32];
    const int bn = blockIdx.x, bm = blockIdx.y;
    const int tid = threadIdx.x;
    const int w = tid >> 6, l = tid & 63;
    const int wm = (w >> 1) * 64, wn = (w & 1) * 64;
    const int lr = l & 15, lk = (l >> 4) * 8;

    f32x4 acc[4][4];
#pragma unroll
    for (int mi = 0; mi < 4; mi++)
#pragma unroll
        for (int ni = 0; ni < 4; ni++) acc[mi][ni] = (f32x4)0.0f;

    const float* Ablk = A + (size_t)bm * 128 * K;
    const float* Bblk = B + (size_t)bn * 128 * K;

    for (int k0 = 0; k0 < K; k0 += 32) {
#pragma unroll
        for (int s = 0; s < 2; ++s) {
            int ch = tid + s * 256;
            int r = ch >> 2, kc = (ch & 3) * 8;
            ((short8*)As)[ch] = cvt8(Ablk + (size_t)r * K + k0 + kc);
            ((short8*)Bs)[ch] = cvt8(Bblk + (size_t)r * K + k0 + kc);
        }
        __syncthreads();
        short8 af[4], bfr[4];
#pragma unroll
        for (int mi = 0; mi < 4; mi++)
            af[mi] = *(const short8*)&As[(wm + mi * 16 + lr) * 32 + lk];
#pragma unroll
        for (int ni = 0; ni < 4; ni++)
            bfr[ni] = *(const short8*)&Bs[(wn + ni * 16 + lr) * 32 + lk];
#pragma unroll
        for (int mi = 0; mi < 4; mi++)
#pragma unroll
            for (int ni = 0; ni < 4; ni++)
                acc[mi][ni] = __builtin_amdgcn_mfma_f32_16x16x32_bf16(
                    af[mi], bfr[ni], acc[mi][ni], 0, 0, 0);
        __syncthreads();
    }

    const int cr = (l >> 4) * 4, cc = l & 15;
#pragma unroll
    for (int mi = 0; mi < 4; mi++) {
#pragma unroll
        for (int ni = 0; ni < 4; ni++) {
            int col = bn * 128 + wn + ni * 16 + cc;
            float bias = bih[col] + bhh[col];
#pragma unroll
            for (int r = 0; r < 4; r++) {
                int row = bm * 128 + wm + mi * 16 + cr + r;
                C[(size_t)row * N + col] = (_Float16)(acc[mi][ni][r] + bias);
            }
        }
    }
}

// ---------------- Persistent recurrent kernel ----------------
// 256 WGs x 512 threads. WG b owns 64 W_hh rows {g*4096+16b+u}.
// Per thread 8 rows x 64 cols: chunks 0..5 in VGPRs (in-loop asm pin),
// chunks 6..7 in LDS (128 KiB). Fence-free step barrier: per-WG monotonic
// flags + agent-scope (sc1) h exchange -> NO L2 writeback/invalidate per step.
__global__ __launch_bounds__(512, 2) void lstm_seq(
        const _Float16* __restrict__ W,      // f16 [16384][4096]
        const _Float16* __restrict__ G,      // f16 [2048][16384]
        const float* __restrict__ Wlin,      // [4096]
        _Float16* __restrict__ hbuf,         // f16 [2][4096]
        unsigned* __restrict__ flags,        // [256] monotonic step flags
        float* __restrict__ praw_part) {     // [256][2048]
    extern __shared__ char smem[];
    _Float16* wl  = (_Float16*)smem;                  // [128][512] = 128 KiB
    _Float16* hl  = (_Float16*)(smem + 131072);       // [4096]     = 8 KiB
    float*    part = (float*)(smem + 131072 + 8192);  // [64][65]   = 16.25 KiB
    unsigned* hl32 = (unsigned*)hl;

    const int tid = threadIdx.x;
    const int w = tid >> 6, l = tid & 63;
    const int bid = blockIdx.x;
    const int base = bid * 16;

    // ---- one-time: load persistent weights ----
    half8_t wr[8][6];
#pragma unroll
    for (int rr = 0; rr < 8; ++rr) {
        const int rl = w * 8 + rr;
        const size_t grow = (size_t)((rl >> 4) * H_DIM + base + (rl & 15));
        const _Float16* wp = W + grow * H_DIM + l * 8;
#pragma unroll
        for (int c = 0; c < 6; ++c)
            wr[rr][c] = *(const half8_t*)(wp + c * 512);
    }
    for (int i = tid; i < 8192; i += 512) {   // LDS part: chunks 6,7
        int col8 = i & 63;
        int cr   = i >> 6;                    // rl*2 + c2
        int rl = cr >> 1, c2 = cr & 1;
        size_t grow = (size_t)((rl >> 4) * H_DIM + base + (rl & 15));
        *(half8_t*)(wl + cr * 512 + col8 * 8) =
            *(const half8_t*)(W + grow * H_DIM + (6 + c2) * 512 + col8 * 8);
    }

    // loop-invariant hoists
    const float wlin = (tid < 16) ? Wlin[base + tid] : 0.0f;
    const int grow_g = (tid >> 4) * H_DIM + base + (tid & 15);  // valid for tid<64
    const _Float16* wlbase = wl + (w * 16) * 512 + l * 8;
    const _Float16* hlbase = hl + l * 8;
    unsigned short* hb16 = (unsigned short*)hbuf;

    float creg = 0.0f;

#pragma unroll 1
    for (int t = 0; t < T_STEPS; ++t) {
        // ---- pin the 48 weight tuples in VGPRs (asm executes every iter,
        // redefining them -> allocator must keep them register-resident) ----
#pragma unroll
        for (int rr = 0; rr < 8; ++rr)
#pragma unroll
            for (int c = 0; c < 6; ++c) {
                f32x4 tmp = __builtin_bit_cast(f32x4, wr[rr][c]);
                asm volatile("" : "+v"(tmp));
                wr[rr][c] = __builtin_bit_cast(half8_t, tmp);
            }

        // prefetch this step's input-projection values (wave 0 only)
        float gval = 0.0f;
        if (tid < 64) gval = (float)G[(size_t)t * G_DIM + grow_g];

        // ---- h readback: agent-scope coalesced u32 loads -> LDS ----
        const unsigned* hsrc = (const unsigned*)hbuf + ((t & 1) << 11); // 2048 u32
#pragma unroll
        for (int k = 0; k < 4; ++k)
            hl32[k * 512 + tid] = __hip_atomic_load(hsrc + k * 512 + tid,
                                                    __ATOMIC_RELAXED,
                                                    __HIP_MEMORY_SCOPE_AGENT);
        __syncthreads();

        float acc[8];
#pragma unroll
        for (int rr = 0; rr < 8; ++rr) acc[rr] = 0.0f;

#pragma unroll
        for (int c = 0; c < 6; ++c) {
            half8_t hv = *(const half8_t*)(hlbase + c * 512);
#pragma unroll
            for (int rr = 0; rr < 8; ++rr)
                acc[rr] = dot8f(wr[rr][c], hv, acc[rr]);
        }
#pragma unroll
        for (int c2 = 0; c2 < 2; ++c2) {
            half8_t hv = *(const half8_t*)(hlbase + (6 + c2) * 512);
#pragma unroll
            for (int rr = 0; rr < 8; ++rr) {
                half8_t wv = *(const half8_t*)(wlbase + (rr * 2 + c2) * 512);
                acc[rr] = dot8f(wv, hv, acc[rr]);
            }
        }
#pragma unroll
        for (int rr = 0; rr < 8; ++rr)
            part[(w * 8 + rr) * 65 + l] = acc[rr];
        __syncthreads();

        if (tid < 64) {
            const float* pr = part + tid * 65;
            float s0 = 0.f, s1 = 0.f, s2 = 0.f, s3 = 0.f;
#pragma unroll
            for (int j = 0; j < 16; ++j) {
                s0 += pr[4 * j + 0]; s1 += pr[4 * j + 1];
                s2 += pr[4 * j + 2]; s3 += pr[4 * j + 3];
            }
            float s = (s0 + s1) + (s2 + s3) + gval;
            float fv = __shfl(s, (tid & 15) + 16);
            float gv = __shfl(s, (tid & 15) + 32);
            float ov = __shfl(s, (tid & 15) + 48);
            if (tid < 16) {
                float c = sigmoidf_(fv) * creg + sigmoidf_(s) * tanhf(gv);
                creg = c;
                float hv = sigmoidf_(ov) * tanhf(c);
                unsigned short hb = __builtin_bit_cast(unsigned short, (_Float16)hv);
                __hip_atomic_store(hb16 + (((t + 1) & 1) << 12) + base + tid, hb,
                                   __ATOMIC_RELAXED, __HIP_MEMORY_SCOPE_AGENT);
                float pp = hv * wlin;
                pp += __shfl_xor(pp, 8, 16);
                pp += __shfl_xor(pp, 4, 16);
                pp += __shfl_xor(pp, 2, 16);
                pp += __shfl_xor(pp, 1, 16);
                if (tid == 0) praw_part[(size_t)bid * T_STEPS + t] = pp;
            }
        }

        // ---- fence-free device barrier (wave 0 spins, others park at barrier) ----
        if (w == 0) {
            asm volatile("s_waitcnt vmcnt(0)" ::: "memory");
            if (tid == 0)
                __hip_atomic_store(flags + bid, (unsigned)(t + 1),
                                   __ATOMIC_RELAXED, __HIP_MEMORY_SCOPE_AGENT);
            const unsigned tgt = (unsigned)(t + 1);
            for (;;) {
                unsigned f0 = __hip_atomic_load(flags + l,       __ATOMIC_RELAXED, __HIP_MEMORY_SCOPE_AGENT);
                unsigned f1 = __hip_atomic_load(flags + l + 64,  __ATOMIC_RELAXED, __HIP_MEMORY_SCOPE_AGENT);
                unsigned f2 = __hip_atomic_load(flags + l + 128, __ATOMIC_RELAXED, __HIP_MEMORY_SCOPE_AGENT);
                unsigned f3 = __hip_atomic_load(flags + l + 192, __ATOMIC_RELAXED, __HIP_MEMORY_SCOPE_AGENT);
                bool ok = (f0 >= tgt) & (f1 >= tgt) & (f2 >= tgt) & (f3 >= tgt);
                if (__all(ok)) break;
                __builtin_amdgcn_s_sleep(1);
            }
        }
        __syncthreads();
    }
}

__global__ void finalize_out(const float* __restrict__ praw_part,
                             const float* __restrict__ blin,
                             float* __restrict__ out, int n) {
    int i = blockIdx.x * blockDim.x + threadIdx.x;
    if (i < n) {
        float s = blin[0];
        for (int wg = 0; wg < 256; ++wg)
            s += praw_part[(size_t)wg * T_STEPS + i];
        out[i] = 1.0f / (1.0f + __expf(-s));
    }
}

// ---------------- launch ----------------
extern "C" void kernel_launch(void* const* d_in, const int* in_sizes, int n_in,
                              void* d_out, int out_size, void* d_ws, size_t ws_size,
                              hipStream_t stream) {
    const float* X    = (const float*)d_in[0];   // [2048][2048]
    const float* Wih  = (const float*)d_in[1];   // [16384][2048]
    const float* Whh  = (const float*)d_in[2];   // [16384][4096]
    const float* bih  = (const float*)d_in[3];   // [16384]
    const float* bhh  = (const float*)d_in[4];   // [16384]
    const float* Wlin = (const float*)d_in[5];   // [4096]
    const float* blin = (const float*)d_in[6];   // [1]
    float* out = (float*)d_out;                  // [2048]

    char* ws = (char*)d_ws;
    // layout (bytes):
    //   Whh16 (f16): 0          .. 134217728
    //   G     (f16): 134217728  .. 201326592
    //   flags      : 201326592  .. +1024      (256 u32)
    //   hbuf  (f16): 201327616  .. +16384     (2*4096*2)
    //   praw_part  : 201344000  .. +2097152
    _Float16* Whh16 = (_Float16*)(ws);
    _Float16* G     = (_Float16*)(ws + 134217728);
    unsigned* flags = (unsigned*)(ws + 201326592);
    _Float16* hbuf  = (_Float16*)(ws + 201327616);
    float* praw_part = (float*)(ws + 201344000);

    convert_f32_f16<<<dim3(2048), dim3(256), 0, stream>>>(Whh, Whh16,
                                                          (16384 * 4096) / 8);
    // zero flags + both h parity buffers (contiguous region, 4352 floats)
    zero_f32<<<dim3(17), dim3(256), 0, stream>>>((float*)flags, 4352);
    gemm_bt<<<dim3(128, 16), dim3(256), 0, stream>>>(X, Wih, bih, bhh, G,
                                                     2048, 16384, 2048);

    hipFuncSetAttribute((const void*)lstm_seq,
                        hipFuncAttributeMaxDynamicSharedMemorySize, 160 * 1024);

    void* args[] = { (void*)&Whh16, (void*)&G, (void*)&Wlin,
                     (void*)&hbuf, (void*)&flags, (void*)&praw_part };
    hipLaunchCooperativeKernel((void*)lstm_seq, dim3(256), dim3(512),
                               args, 155904, stream);

    finalize_out<<<dim3(8), dim3(256), 0, stream>>>(praw_part, blin, out, 2048);
}

// Round 5
// 17686.633 us; speedup vs baseline: 4.8440x; 1.0033x over previous
//
#include <hip/hip_runtime.h>

typedef short  short8 __attribute__((ext_vector_type(8)));
typedef float  f32x4  __attribute__((ext_vector_type(4)));
typedef _Float16 half8_t __attribute__((ext_vector_type(8)));
typedef _Float16 half2_t __attribute__((ext_vector_type(2)));

#define T_STEPS 2048
#define I_DIM   2048
#define H_DIM   4096
#define G_DIM   16384   // 4*H

__device__ __forceinline__ unsigned short f2bf(float x) {
    union { float f; unsigned int u; } v; v.f = x;
    unsigned int u = v.u;
    return (unsigned short)((u + 0x7FFFu + ((u >> 16) & 1u)) >> 16);
}
__device__ __forceinline__ float sigmoidf_(float x) {
    return 1.0f / (1.0f + __expf(-x));
}

__device__ __forceinline__ float dot2f(half2_t a, half2_t b, float acc) {
#if __has_builtin(__builtin_amdgcn_fdot2)
    return __builtin_amdgcn_fdot2(a, b, acc, false);
#else
    return fmaf((float)a[0], (float)b[0], fmaf((float)a[1], (float)b[1], acc));
#endif
}
__device__ __forceinline__ float dot8f(half8_t a, half8_t b, float acc) {
    acc = dot2f(__builtin_shufflevector(a, a, 0, 1), __builtin_shufflevector(b, b, 0, 1), acc);
    acc = dot2f(__builtin_shufflevector(a, a, 2, 3), __builtin_shufflevector(b, b, 2, 3), acc);
    acc = dot2f(__builtin_shufflevector(a, a, 4, 5), __builtin_shufflevector(b, b, 4, 5), acc);
    acc = dot2f(__builtin_shufflevector(a, a, 6, 7), __builtin_shufflevector(b, b, 6, 7), acc);
    return acc;
}

// ---------------- f32 -> f16 conversion (for W_hh) ----------------
__global__ void convert_f32_f16(const float* __restrict__ in,
                                _Float16* __restrict__ out, int n8) {
    int i = blockIdx.x * blockDim.x + threadIdx.x;
    int stride = gridDim.x * blockDim.x;
    for (; i < n8; i += stride) {
        f32x4 a = *(const f32x4*)(in + (size_t)i * 8);
        f32x4 b = *(const f32x4*)(in + (size_t)i * 8 + 4);
        half8_t o;
        o[0] = (_Float16)a[0]; o[1] = (_Float16)a[1];
        o[2] = (_Float16)a[2]; o[3] = (_Float16)a[3];
        o[4] = (_Float16)b[0]; o[5] = (_Float16)b[1];
        o[6] = (_Float16)b[2]; o[7] = (_Float16)b[3];
        *(half8_t*)(out + (size_t)i * 8) = o;
    }
}

__global__ void zero_f32(float* __restrict__ p, int n) {
    int i = blockIdx.x * blockDim.x + threadIdx.x;
    int stride = gridDim.x * blockDim.x;
    for (; i < n; i += stride) p[i] = 0.0f;
}

// ---------------- GEMM: G[t][r] = sum_k X[t][k]*W_ih[r][k] + bih[r]+bhh[r] ----------------
__device__ __forceinline__ short8 cvt8(const float* __restrict__ p) {
    f32x4 a = *(const f32x4*)p;
    f32x4 b = *(const f32x4*)(p + 4);
    short8 r;
    r[0] = (short)f2bf(a[0]); r[1] = (short)f2bf(a[1]);
    r[2] = (short)f2bf(a[2]); r[3] = (short)f2bf(a[3]);
    r[4] = (short)f2bf(b[0]); r[5] = (short)f2bf(b[1]);
    r[6] = (short)f2bf(b[2]); r[7] = (short)f2bf(b[3]);
    return r;
}

__global__ __launch_bounds__(256) void gemm_bt(const float* __restrict__ A,
                                               const float* __restrict__ B,
                                               const float* __restrict__ bih,
                                               const float* __restrict__ bhh,
                                               _Float16* __restrict__ C,
                                               int M, int N, int K) {
    __shared__ unsigned short As[128 * 32];
    __shared__ unsigned short Bs[128 * 32];
    const int bn = blockIdx.x, bm = blockIdx.y;
    const int tid = threadIdx.x;
    const int w = tid >> 6, l = tid & 63;
    const int wm = (w >> 1) * 64, wn = (w & 1) * 64;
    const int lr = l & 15, lk = (l >> 4) * 8;

    f32x4 acc[4][4];
#pragma unroll
    for (int mi = 0; mi < 4; mi++)
#pragma unroll
        for (int ni = 0; ni < 4; ni++) acc[mi][ni] = (f32x4)0.0f;

    const float* Ablk = A + (size_t)bm * 128 * K;
    const float* Bblk = B + (size_t)bn * 128 * K;

    for (int k0 = 0; k0 < K; k0 += 32) {
#pragma unroll
        for (int s = 0; s < 2; ++s) {
            int ch = tid + s * 256;
            int r = ch >> 2, kc = (ch & 3) * 8;
            ((short8*)As)[ch] = cvt8(Ablk + (size_t)r * K + k0 + kc);
            ((short8*)Bs)[ch] = cvt8(Bblk + (size_t)r * K + k0 + kc);
        }
        __syncthreads();
        short8 af[4], bfr[4];
#pragma unroll
        for (int mi = 0; mi < 4; mi++)
            af[mi] = *(const short8*)&As[(wm + mi * 16 + lr) * 32 + lk];
#pragma unroll
        for (int ni = 0; ni < 4; ni++)
            bfr[ni] = *(const short8*)&Bs[(wn + ni * 16 + lr) * 32 + lk];
#pragma unroll
        for (int mi = 0; mi < 4; mi++)
#pragma unroll
            for (int ni = 0; ni < 4; ni++)
                acc[mi][ni] = __builtin_amdgcn_mfma_f32_16x16x32_bf16(
                    af[mi], bfr[ni], acc[mi][ni], 0, 0, 0);
        __syncthreads();
    }

    const int cr = (l >> 4) * 4, cc = l & 15;
#pragma unroll
    for (int mi = 0; mi < 4; mi++) {
#pragma unroll
        for (int ni = 0; ni < 4; ni++) {
            int col = bn * 128 + wn + ni * 16 + cc;
            float bias = bih[col] + bhh[col];
#pragma unroll
            for (int r = 0; r < 4; r++) {
                int row = bm * 128 + wm + mi * 16 + cr + r;
                C[(size_t)row * N + col] = (_Float16)(acc[mi][ni][r] + bias);
            }
        }
    }
}

// ---------------- Persistent recurrent kernel ----------------
// 256 WGs x 512 threads, 1 WG/CU. WG b owns 64 W_hh rows {g*4096+16b+u}.
// Per thread 8 rows x 64 cols. Chunks 0..5 (192 VGPRs) loaded ONCE via opaque
// inline-asm global_load_dwordx4 -> cannot be rematerialized, must stay
// register-resident (r2-r4: every compiler-visible load got re-issued per step,
// streaming 96 MB/step from L3). Chunks 6..7 in LDS (128 KiB).
// Fence-free step barrier: per-WG monotonic flags, agent-scope (sc1) h exchange.
__global__ __launch_bounds__(512, 2) void lstm_seq(
        const _Float16* __restrict__ W,      // f16 [16384][4096]
        const _Float16* __restrict__ G,      // f16 [2048][16384]
        const float* __restrict__ Wlin,      // [4096]
        _Float16* __restrict__ hbuf,         // f16 [2][4096]
        unsigned* __restrict__ flags,        // [256] monotonic step flags
        float* __restrict__ praw_part) {     // [256][2048]
    extern __shared__ char smem[];
    _Float16* wl  = (_Float16*)smem;                  // [128][512] = 128 KiB
    _Float16* hl  = (_Float16*)(smem + 131072);       // [4096]     = 8 KiB
    float*    part = (float*)(smem + 131072 + 8192);  // [64][65]   = 16.25 KiB
    unsigned* hl32 = (unsigned*)hl;

    const int tid = threadIdx.x;
    const int w = tid >> 6, l = tid & 63;
    const int bid = blockIdx.x;
    const int base = bid * 16;

    // ---- one-time: opaque register-resident weight load (chunks 0..5) ----
    half8_t wr[8][6];
#pragma unroll
    for (int rr = 0; rr < 8; ++rr) {
        const int rl = w * 8 + rr;
        const size_t grow = (size_t)((rl >> 4) * H_DIM + base + (rl & 15));
        const _Float16* wp = W + grow * H_DIM + l * 8;
#pragma unroll
        for (int c = 0; c < 6; ++c) {
            f32x4 tmp;
            asm volatile("global_load_dwordx4 %0, %1, off"
                         : "=v"(tmp) : "v"(wp + c * 512));
            wr[rr][c] = __builtin_bit_cast(half8_t, tmp);
        }
    }
    asm volatile("s_waitcnt vmcnt(0)" ::: "memory");
    __builtin_amdgcn_sched_barrier(0);

    for (int i = tid; i < 8192; i += 512) {   // LDS part: chunks 6,7
        int col8 = i & 63;
        int cr   = i >> 6;                    // rl*2 + c2
        int rl = cr >> 1, c2 = cr & 1;
        size_t grow = (size_t)((rl >> 4) * H_DIM + base + (rl & 15));
        *(half8_t*)(wl + cr * 512 + col8 * 8) =
            *(const half8_t*)(W + grow * H_DIM + (6 + c2) * 512 + col8 * 8);
    }

    // loop-invariant hoists
    const float wlin = (tid < 16) ? Wlin[base + tid] : 0.0f;
    const int grow_g = (tid >> 4) * H_DIM + base + (tid & 15);  // valid for tid<64
    const _Float16* wlbase = wl + (w * 16) * 512 + l * 8;
    const _Float16* hlbase = hl + l * 8;
    unsigned short* hb16 = (unsigned short*)hbuf;

    float creg = 0.0f;

#pragma unroll 1
    for (int t = 0; t < T_STEPS; ++t) {
        // prefetch this step's input-projection values (wave 0 only)
        float gval = 0.0f;
        if (tid < 64) gval = (float)G[(size_t)t * G_DIM + grow_g];

        // ---- h readback: agent-scope coalesced u32 loads -> LDS ----
        const unsigned* hsrc = (const unsigned*)hbuf + ((t & 1) << 11); // 2048 u32
#pragma unroll
        for (int k = 0; k < 4; ++k)
            hl32[k * 512 + tid] = __hip_atomic_load(hsrc + k * 512 + tid,
                                                    __ATOMIC_RELAXED,
                                                    __HIP_MEMORY_SCOPE_AGENT);
        __syncthreads();

        float acc[8];
#pragma unroll
        for (int rr = 0; rr < 8; ++rr) acc[rr] = 0.0f;

#pragma unroll
        for (int c = 0; c < 6; ++c) {
            half8_t hv = *(const half8_t*)(hlbase + c * 512);
#pragma unroll
            for (int rr = 0; rr < 8; ++rr)
                acc[rr] = dot8f(wr[rr][c], hv, acc[rr]);
        }
#pragma unroll
        for (int c2 = 0; c2 < 2; ++c2) {
            half8_t hv = *(const half8_t*)(hlbase + (6 + c2) * 512);
#pragma unroll
            for (int rr = 0; rr < 8; ++rr) {
                half8_t wv = *(const half8_t*)(wlbase + (rr * 2 + c2) * 512);
                acc[rr] = dot8f(wv, hv, acc[rr]);
            }
        }
#pragma unroll
        for (int rr = 0; rr < 8; ++rr)
            part[(w * 8 + rr) * 65 + l] = acc[rr];
        __syncthreads();

        if (tid < 64) {
            const float* pr = part + tid * 65;
            float s0 = 0.f, s1 = 0.f, s2 = 0.f, s3 = 0.f;
#pragma unroll
            for (int j = 0; j < 16; ++j) {
                s0 += pr[4 * j + 0]; s1 += pr[4 * j + 1];
                s2 += pr[4 * j + 2]; s3 += pr[4 * j + 3];
            }
            float s = (s0 + s1) + (s2 + s3) + gval;
            float fv = __shfl(s, (tid & 15) + 16);
            float gv = __shfl(s, (tid & 15) + 32);
            float ov = __shfl(s, (tid & 15) + 48);
            if (tid < 16) {
                float c = sigmoidf_(fv) * creg + sigmoidf_(s) * tanhf(gv);
                creg = c;
                float hv = sigmoidf_(ov) * tanhf(c);
                unsigned short hb = __builtin_bit_cast(unsigned short, (_Float16)hv);
                __hip_atomic_store(hb16 + (((t + 1) & 1) << 12) + base + tid, hb,
                                   __ATOMIC_RELAXED, __HIP_MEMORY_SCOPE_AGENT);
                float pp = hv * wlin;
                pp += __shfl_xor(pp, 8, 16);
                pp += __shfl_xor(pp, 4, 16);
                pp += __shfl_xor(pp, 2, 16);
                pp += __shfl_xor(pp, 1, 16);
                if (tid == 0) praw_part[(size_t)bid * T_STEPS + t] = pp;
            }
        }

        // ---- fence-free device barrier (wave 0 spins, others park) ----
        if (w == 0) {
            asm volatile("s_waitcnt vmcnt(0)" ::: "memory");
            if (tid == 0)
                __hip_atomic_store(flags + bid, (unsigned)(t + 1),
                                   __ATOMIC_RELAXED, __HIP_MEMORY_SCOPE_AGENT);
            const unsigned tgt = (unsigned)(t + 1);
            for (;;) {
                unsigned f0 = __hip_atomic_load(flags + l,       __ATOMIC_RELAXED, __HIP_MEMORY_SCOPE_AGENT);
                unsigned f1 = __hip_atomic_load(flags + l + 64,  __ATOMIC_RELAXED, __HIP_MEMORY_SCOPE_AGENT);
                unsigned f2 = __hip_atomic_load(flags + l + 128, __ATOMIC_RELAXED, __HIP_MEMORY_SCOPE_AGENT);
                unsigned f3 = __hip_atomic_load(flags + l + 192, __ATOMIC_RELAXED, __HIP_MEMORY_SCOPE_AGENT);
                bool ok = (f0 >= tgt) & (f1 >= tgt) & (f2 >= tgt) & (f3 >= tgt);
                if (__all(ok)) break;
                __builtin_amdgcn_s_sleep(1);
            }
        }
        __syncthreads();
    }
}

__global__ void finalize_out(const float* __restrict__ praw_part,
                             const float* __restrict__ blin,
                             float* __restrict__ out, int n) {
    int i = blockIdx.x * blockDim.x + threadIdx.x;
    if (i < n) {
        float s = blin[0];
        for (int wg = 0; wg < 256; ++wg)
            s += praw_part[(size_t)wg * T_STEPS + i];
        out[i] = 1.0f / (1.0f + __expf(-s));
    }
}

// ---------------- launch ----------------
extern "C" void kernel_launch(void* const* d_in, const int* in_sizes, int n_in,
                              void* d_out, int out_size, void* d_ws, size_t ws_size,
                              hipStream_t stream) {
    const float* X    = (const float*)d_in[0];   // [2048][2048]
    const float* Wih  = (const float*)d_in[1];   // [16384][2048]
    const float* Whh  = (const float*)d_in[2];   // [16384][4096]
    const float* bih  = (const float*)d_in[3];   // [16384]
    const float* bhh  = (const float*)d_in[4];   // [16384]
    const float* Wlin = (const float*)d_in[5];   // [4096]
    const float* blin = (const float*)d_in[6];   // [1]
    float* out = (float*)d_out;                  // [2048]

    char* ws = (char*)d_ws;
    // layout (bytes):
    //   Whh16 (f16): 0          .. 134217728
    //   G     (f16): 134217728  .. 201326592
    //   flags      : 201326592  .. +1024      (256 u32)
    //   hbuf  (f16): 201327616  .. +16384     (2*4096*2)
    //   praw_part  : 201344000  .. +2097152
    _Float16* Whh16 = (_Float16*)(ws);
    _Float16* G     = (_Float16*)(ws + 134217728);
    unsigned* flags = (unsigned*)(ws + 201326592);
    _Float16* hbuf  = (_Float16*)(ws + 201327616);
    float* praw_part = (float*)(ws + 201344000);

    convert_f32_f16<<<dim3(2048), dim3(256), 0, stream>>>(Whh, Whh16,
                                                          (16384 * 4096) / 8);
    // zero flags + both h parity buffers (contiguous region, 4352 floats)
    zero_f32<<<dim3(17), dim3(256), 0, stream>>>((float*)flags, 4352);
    gemm_bt<<<dim3(128, 16), dim3(256), 0, stream>>>(X, Wih, bih, bhh, G,
                                                     2048, 16384, 2048);

    hipFuncSetAttribute((const void*)lstm_seq,
                        hipFuncAttributeMaxDynamicSharedMemorySize, 160 * 1024);

    void* args[] = { (void*)&Whh16, (void*)&G, (void*)&Wlin,
                     (void*)&hbuf, (void*)&flags, (void*)&praw_part };
    hipLaunchCooperativeKernel((void*)lstm_seq, dim3(256), dim3(512),
                               args, 155904, stream);

    finalize_out<<<dim3(8), dim3(256), 0, stream>>>(praw_part, blin, out, 2048);
}